// Round 1
// baseline (519.974 us; speedup 1.0000x reference)
//
#include <hip/hip_runtime.h>

#define S_LEN 2048
#define DM 2048
#define NH 16
#define DK 128
#define BB 2
#define BH (BB*NH)

typedef float f32x4 __attribute__((ext_vector_type(4)));
typedef __bf16 bf16x8 __attribute__((ext_vector_type(8)));

__device__ inline ushort f2bf(float f){
  unsigned u = __float_as_uint(f);
  u = (u + 0x7FFFu + ((u >> 16) & 1u)) >> 16;
  return (ushort)u;
}

// ---------------- fp32 -> bf16 (vectorized) ----------------
__global__ void k_f32_to_bf16(const float* __restrict__ in, ushort* __restrict__ out, int n4){
  int i = blockIdx.x * blockDim.x + threadIdx.x;
  if (i >= n4) return;
  float4 v = reinterpret_cast<const float4*>(in)[i];
  ushort4 o;
  o.x = f2bf(v.x); o.y = f2bf(v.y); o.z = f2bf(v.z); o.w = f2bf(v.w);
  reinterpret_cast<ushort4*>(out)[i] = o;
}

// ---------------- rope cos/sin table [S][64] ----------------
__global__ void k_rope_table(const int* __restrict__ pos, float* __restrict__ ct, float* __restrict__ st){
  int idx = blockIdx.x * 256 + threadIdx.x;
  if (idx >= S_LEN * 64) return;
  int s = idx >> 6, i = idx & 63;
  // inv_freq = 10000^(-i/64) = exp(-ln(10000)/64 * i)
  float inv = expf(-0.14391156831212787f * (float)i);
  float f = (float)pos[s] * inv;
  ct[idx] = cosf(f);
  st[idx] = sinf(f);
}

// ---------------- GEMM: C[M][N] = A[M][K] * Bt[N][K]^T (bf16 in, fp32 out) ----------------
// 128x128 tile, BK=32, 4 waves (2x2), 16x16x32 MFMA. Simple 2-barrier loop, reg-staged LDS.
__launch_bounds__(256)
__global__ void k_gemm_bt(const ushort* __restrict__ A, const ushort* __restrict__ Bt,
                          float* __restrict__ C, int M, int N, int K){
  __shared__ short lA[128 * 40];   // +8 bf16 pad -> 2-way bank conflicts only
  __shared__ short lB[128 * 40];
  const int tid = threadIdx.x;
  const int lane = tid & 63, wid = tid >> 6;
  const int wm = wid >> 1, wn = wid & 1;
  const int bx = blockIdx.x, by = blockIdx.y;

  const int r0 = tid >> 2, c0 = (tid & 3) * 8;   // staging chunk (16B per thread, x2)
  const ushort* pa0 = A  + (size_t)(by * 128 + r0)      * K + c0;
  const ushort* pa1 = A  + (size_t)(by * 128 + r0 + 64) * K + c0;
  const ushort* pb0 = Bt + (size_t)(bx * 128 + r0)      * K + c0;
  const ushort* pb1 = Bt + (size_t)(bx * 128 + r0 + 64) * K + c0;
  short* wA0 = &lA[r0 * 40 + c0];        short* wA1 = &lA[(r0 + 64) * 40 + c0];
  short* wB0 = &lB[r0 * 40 + c0];        short* wB1 = &lB[(r0 + 64) * 40 + c0];

  f32x4 acc[4][4] = {};
  const int arow = wm * 64, brow = wn * 64;
  const int fr = lane & 15, fk = (lane >> 4) * 8;

  for (int kk = 0; kk < K; kk += 32){
    bf16x8 ra0 = *reinterpret_cast<const bf16x8*>(pa0 + kk);
    bf16x8 ra1 = *reinterpret_cast<const bf16x8*>(pa1 + kk);
    bf16x8 rb0 = *reinterpret_cast<const bf16x8*>(pb0 + kk);
    bf16x8 rb1 = *reinterpret_cast<const bf16x8*>(pb1 + kk);
    __syncthreads();
    *reinterpret_cast<bf16x8*>(wA0) = ra0;
    *reinterpret_cast<bf16x8*>(wA1) = ra1;
    *reinterpret_cast<bf16x8*>(wB0) = rb0;
    *reinterpret_cast<bf16x8*>(wB1) = rb1;
    __syncthreads();
    bf16x8 af[4], bfg[4];
    #pragma unroll
    for (int m = 0; m < 4; m++)
      af[m] = *reinterpret_cast<const bf16x8*>(&lA[(arow + m * 16 + fr) * 40 + fk]);
    #pragma unroll
    for (int n = 0; n < 4; n++)
      bfg[n] = *reinterpret_cast<const bf16x8*>(&lB[(brow + n * 16 + fr) * 40 + fk]);
    #pragma unroll
    for (int m = 0; m < 4; m++)
      #pragma unroll
      for (int n = 0; n < 4; n++)
        acc[m][n] = __builtin_amdgcn_mfma_f32_16x16x32_bf16(af[m], bfg[n], acc[m][n], 0, 0, 0);
  }
  const int orow = by * 128 + wm * 64 + (lane >> 4) * 4;
  const int ocol = bx * 128 + wn * 64 + (lane & 15);
  #pragma unroll
  for (int m = 0; m < 4; m++)
    #pragma unroll
    for (int n = 0; n < 4; n++)
      #pragma unroll
      for (int i = 0; i < 4; i++)
        C[(size_t)(orow + m * 16 + i) * N + ocol + n * 16] = acc[m][n][i];
}

// ---------------- RoPE apply + [b][s][e] -> [b][h][s][d] transpose + bf16 quantize ----------------
__global__ void k_rope_apply(const float* __restrict__ X, const float* __restrict__ ct,
                             const float* __restrict__ st, ushort* __restrict__ out){
  int idx = blockIdx.x * 256 + threadIdx.x;     // (((b*S+s)*H)+h)*64 + i
  if (idx >= BB * S_LEN * NH * 64) return;
  int i = idx & 63; int t = idx >> 6;
  int h = t & (NH - 1); t >>= 4;
  int s = t & (S_LEN - 1); int b = t >> 11;
  float2 eo = reinterpret_cast<const float2*>(X + (size_t)(b * S_LEN + s) * DM + h * DK)[i];
  float c = ct[s * 64 + i], sn = st[s * 64 + i];
  float oe = eo.x * c - eo.y * sn;
  float oo = eo.x * sn + eo.y * c;
  unsigned pack = (unsigned)f2bf(oe) | ((unsigned)f2bf(oo) << 16);
  reinterpret_cast<unsigned*>(out + ((size_t)(b * NH + h) * S_LEN + s) * DK)[i] = pack;
}

// ---------------- V: [b][s][e] -> Vt[b][h][d][s] bf16 (tiled transpose) ----------------
__global__ void k_vtrans(const float* __restrict__ X, ushort* __restrict__ Vt){
  __shared__ float tile[32][33];
  int s0 = blockIdx.x * 32, d0 = blockIdx.y * 32;
  int bh = blockIdx.z; int b = bh >> 4, h = bh & 15;
  int t = threadIdx.x;
  int r = t >> 3, c4 = (t & 7) * 4;
  float4 v = *reinterpret_cast<const float4*>(X + (size_t)(b * S_LEN + s0 + r) * DM + h * DK + d0 + c4);
  tile[r][c4] = v.x; tile[r][c4 + 1] = v.y; tile[r][c4 + 2] = v.z; tile[r][c4 + 3] = v.w;
  __syncthreads();
  int dl = t >> 3, s4 = (t & 7) * 4;
  ushort4 o;
  o.x = f2bf(tile[s4][dl]); o.y = f2bf(tile[s4 + 1][dl]);
  o.z = f2bf(tile[s4 + 2][dl]); o.w = f2bf(tile[s4 + 3][dl]);
  *reinterpret_cast<ushort4*>(Vt + (size_t)(bh * DK + d0 + dl) * S_LEN + s0 + s4) = o;
}

// ---------------- causal flash attention ----------------
// grid: (S/64, B*H). 4 waves; wave w owns q-rows [q0+16w, q0+16w+16). KV tiles of 32.
__launch_bounds__(256)
__global__ void k_attn(const ushort* __restrict__ Q, const ushort* __restrict__ K,
                       const ushort* __restrict__ Vt, ushort* __restrict__ O){
  __shared__ short Kt[32 * 136];     // [k][d] pad 8
  __shared__ short Vl[128 * 40];     // [d][k] pad 8
  __shared__ short Pl[4][16 * 40];   // per-wave P [q][k] pad 8
  const int tid = threadIdx.x, lane = tid & 63, wid = tid >> 6;
  const int bh = blockIdx.y; const int b = bh >> 4, h = bh & 15;
  const int q0 = blockIdx.x * 64;
  const int qr = q0 + wid * 16;
  const int fr = lane & 15, fq = lane >> 4;

  bf16x8 qf[4];
  const ushort* qbase = Q + ((size_t)bh * S_LEN + qr + fr) * DK + fq * 8;
  #pragma unroll
  for (int c = 0; c < 4; c++) qf[c] = *reinterpret_cast<const bf16x8*>(qbase + c * 32);

  float mi[4], li[4];
  #pragma unroll
  for (int i = 0; i < 4; i++){ mi[i] = -1e30f; li[i] = 0.f; }
  f32x4 accO[8] = {};

  const int nt = q0 / 32 + 2;
  const ushort* kb = K  + (size_t)bh * S_LEN * DK;
  const ushort* vb = Vt + (size_t)bh * DK * S_LEN;

  for (int kt = 0; kt < nt; kt++){
    const int k0 = kt * 32;
    __syncthreads();
    #pragma unroll
    for (int rep = 0; rep < 2; rep++){
      int idx = rep * 256 + tid;
      int r = idx >> 4, c = (idx & 15) * 8;
      *reinterpret_cast<bf16x8*>(&Kt[r * 136 + c]) =
        *reinterpret_cast<const bf16x8*>(kb + (size_t)(k0 + r) * DK + c);
    }
    #pragma unroll
    for (int rep = 0; rep < 2; rep++){
      int idx = rep * 256 + tid;
      int d = idx >> 2, c = (idx & 3) * 8;
      *reinterpret_cast<bf16x8*>(&Vl[d * 40 + c]) =
        *reinterpret_cast<const bf16x8*>(vb + (size_t)d * S_LEN + k0 + c);
    }
    __syncthreads();

    f32x4 sc[2] = {};
    #pragma unroll
    for (int ch = 0; ch < 2; ch++)
      #pragma unroll
      for (int c = 0; c < 4; c++){
        bf16x8 kf = *reinterpret_cast<const bf16x8*>(&Kt[(ch * 16 + fr) * 136 + c * 32 + fq * 8]);
        sc[ch] = __builtin_amdgcn_mfma_f32_16x16x32_bf16(qf[c], kf, sc[ch], 0, 0, 0);
      }

    const float scale = 0.08838834764831845f;  // 1/sqrt(128)
    bool needmask = (k0 + 31 > qr);
    #pragma unroll
    for (int ch = 0; ch < 2; ch++)
      #pragma unroll
      for (int i = 0; i < 4; i++){
        float v = sc[ch][i] * scale;
        if (needmask){
          int row = qr + fq * 4 + i, key = k0 + ch * 16 + fr;
          if (key > row) v = -1e30f;
        }
        sc[ch][i] = v;
      }

    f32x4 mx;
    #pragma unroll
    for (int i = 0; i < 4; i++) mx[i] = fmaxf(sc[0][i], sc[1][i]);
    #pragma unroll
    for (int off = 1; off < 16; off <<= 1)
      #pragma unroll
      for (int i = 0; i < 4; i++) mx[i] = fmaxf(mx[i], __shfl_xor(mx[i], off));

    float scl[4];
    #pragma unroll
    for (int i = 0; i < 4; i++){
      float mn = fmaxf(mi[i], mx[i]);
      scl[i] = __expf(mi[i] - mn);
      mi[i] = mn;
    }
    #pragma unroll
    for (int ch = 0; ch < 2; ch++)
      #pragma unroll
      for (int i = 0; i < 4; i++) sc[ch][i] = __expf(sc[ch][i] - mi[i]);

    f32x4 rs;
    #pragma unroll
    for (int i = 0; i < 4; i++) rs[i] = sc[0][i] + sc[1][i];
    #pragma unroll
    for (int off = 1; off < 16; off <<= 1)
      #pragma unroll
      for (int i = 0; i < 4; i++) rs[i] += __shfl_xor(rs[i], off);

    #pragma unroll
    for (int i = 0; i < 4; i++) li[i] = li[i] * scl[i] + rs[i];
    #pragma unroll
    for (int dt = 0; dt < 8; dt++)
      #pragma unroll
      for (int i = 0; i < 4; i++) accO[dt][i] *= scl[i];

    #pragma unroll
    for (int ch = 0; ch < 2; ch++)
      #pragma unroll
      for (int i = 0; i < 4; i++)
        Pl[wid][(fq * 4 + i) * 40 + ch * 16 + fr] = (short)f2bf(sc[ch][i]);
    __syncthreads();

    bf16x8 pf = *reinterpret_cast<const bf16x8*>(&Pl[wid][fr * 40 + fq * 8]);
    #pragma unroll
    for (int dt = 0; dt < 8; dt++){
      bf16x8 vf = *reinterpret_cast<const bf16x8*>(&Vl[(dt * 16 + fr) * 40 + fq * 8]);
      accO[dt] = __builtin_amdgcn_mfma_f32_16x16x32_bf16(pf, vf, accO[dt], 0, 0, 0);
    }
  }

  float inv[4];
  #pragma unroll
  for (int i = 0; i < 4; i++) inv[i] = 1.f / li[i];
  ushort* ob = O + (size_t)b * S_LEN * DM;
  #pragma unroll
  for (int dt = 0; dt < 8; dt++)
    #pragma unroll
    for (int i = 0; i < 4; i++){
      int row = qr + fq * 4 + i;
      int e = h * DK + dt * 16 + fr;
      ob[(size_t)row * DM + e] = f2bf(accO[dt][i] * inv[i]);
    }
}

extern "C" void kernel_launch(void* const* d_in, const int* in_sizes, int n_in,
                              void* d_out, int out_size, void* d_ws, size_t ws_size,
                              hipStream_t stream){
  const float* x  = (const float*)d_in[0];
  const float* wq = (const float*)d_in[1];
  const float* wk = (const float*)d_in[2];
  const float* wv = (const float*)d_in[3];
  const float* wo = (const float*)d_in[4];
  const int* pos  = (const int*)d_in[5];
  float* out = (float*)d_out;

  char* ws = (char*)d_ws;
  // workspace layout (bytes):
  ushort* xb = (ushort*)(ws);                        // 16 MiB  x bf16
  ushort* wb = (ushort*)(ws + 16777216);             //  8 MiB  current weight bf16
  float*  scr = (float*)(ws + 25165824);             // 32 MiB  fp32 projection scratch
  ushort* Ob = (ushort*)(ws + 25165824);             //   (aliases scr after V consumed)
  ushort* Qh = (ushort*)(ws + 58720256);             // 16 MiB
  ushort* Kh = (ushort*)(ws + 75497472);             // 16 MiB
  ushort* Vt = (ushort*)(ws + 92274688);             // 16 MiB
  float*  ct = (float*)(ws + 109051904);             // 512 KiB
  float*  st = (float*)(ws + 109576192);             // 512 KiB  (end ~105 MiB)

  const int M = BB * S_LEN, N = DM, K = DM;
  dim3 gblk(N / 128, M / 128);
  const int nw4 = DM * DM / 4;

  k_f32_to_bf16<<<(M * DM / 4) / 256, 256, 0, stream>>>(x, xb, M * DM / 4);
  k_rope_table<<<(S_LEN * 64) / 256, 256, 0, stream>>>(pos, ct, st);

  k_f32_to_bf16<<<nw4 / 256, 256, 0, stream>>>(wq, wb, nw4);
  k_gemm_bt<<<gblk, 256, 0, stream>>>(xb, wb, scr, M, N, K);
  k_rope_apply<<<(BB * S_LEN * NH * 64) / 256, 256, 0, stream>>>(scr, ct, st, Qh);

  k_f32_to_bf16<<<nw4 / 256, 256, 0, stream>>>(wk, wb, nw4);
  k_gemm_bt<<<gblk, 256, 0, stream>>>(xb, wb, scr, M, N, K);
  k_rope_apply<<<(BB * S_LEN * NH * 64) / 256, 256, 0, stream>>>(scr, ct, st, Kh);

  k_f32_to_bf16<<<nw4 / 256, 256, 0, stream>>>(wv, wb, nw4);
  k_gemm_bt<<<gblk, 256, 0, stream>>>(xb, wb, scr, M, N, K);
  k_vtrans<<<dim3(S_LEN / 32, DK / 32, BH), 256, 0, stream>>>(scr, Vt);

  k_attn<<<dim3(S_LEN / 64, BH), 256, 0, stream>>>(Qh, Kh, Vt, Ob);

  k_f32_to_bf16<<<nw4 / 256, 256, 0, stream>>>(wo, wb, nw4);
  k_gemm_bt<<<gblk, 256, 0, stream>>>(Ob, wb, out, M, N, K);
}

// Round 2
// 507.399 us; speedup vs baseline: 1.0248x; 1.0248x over previous
//
#include <hip/hip_runtime.h>

#define S_LEN 2048
#define DM 2048
#define NH 16
#define DK 128
#define BB 2
#define BH (BB*NH)

typedef float f32x4 __attribute__((ext_vector_type(4)));
typedef __bf16 bf16x8 __attribute__((ext_vector_type(8)));
typedef unsigned int u32;

#define AS1 __attribute__((address_space(1)))
#define AS3 __attribute__((address_space(3)))

__device__ inline void gload16(const void* g, void* l){
  __builtin_amdgcn_global_load_lds((AS1 const u32*)g, (AS3 u32*)l, 16, 0, 0);
}

__device__ inline ushort f2bf(float f){
  unsigned u = __float_as_uint(f);
  u = (u + 0x7FFFu + ((u >> 16) & 1u)) >> 16;
  return (ushort)u;
}

// ---------------- fp32 -> bf16 (vectorized) ----------------
__global__ void k_f32_to_bf16(const float* __restrict__ in, ushort* __restrict__ out, int n4){
  int i = blockIdx.x * blockDim.x + threadIdx.x;
  if (i >= n4) return;
  float4 v = reinterpret_cast<const float4*>(in)[i];
  ushort4 o;
  o.x = f2bf(v.x); o.y = f2bf(v.y); o.z = f2bf(v.z); o.w = f2bf(v.w);
  reinterpret_cast<ushort4*>(out)[i] = o;
}

// ---------------- rope cos/sin table [S][64] ----------------
__global__ void k_rope_table(const int* __restrict__ pos, float* __restrict__ ct, float* __restrict__ st){
  int idx = blockIdx.x * 256 + threadIdx.x;
  if (idx >= S_LEN * 64) return;
  int s = idx >> 6, i = idx & 63;
  float inv = expf(-0.14391156831212787f * (float)i);
  float f = (float)pos[s] * inv;
  ct[idx] = cosf(f);
  st[idx] = sinf(f);
}

// ---------------- GEMM: C[M][N] = A[M][K] * Bt[N][K]^T  (m97 structure) ----------------
// 128x128 tile, BK=32, 4 waves (2x2), global_load_lds width=16, linear LDS, 2-barrier loop.
__launch_bounds__(256)
__global__ void k_gemm_bt(const ushort* __restrict__ A, const ushort* __restrict__ Bt,
                          float* __restrict__ C, int M, int N, int K){
  __shared__ short lA[128 * 32];
  __shared__ short lB[128 * 32];
  const int tid = threadIdx.x;
  const int lane = tid & 63, wid = tid >> 6;
  const int wm = wid >> 1, wn = wid & 1;
  const int bx = blockIdx.x, by = blockIdx.y;
  const int fr = lane & 15, fq = lane >> 4;

  // staging: 8x 1KB wave-instrs (2 per wave per matrix); instr j covers 16 rows.
  const int sr = wid * 32 + (lane >> 2);     // base row (instr 0 of this wave)
  const int scol = (lane & 3) * 8;
  const ushort* pa = A  + (size_t)(by * 128 + sr) * K + scol;
  const ushort* pb = Bt + (size_t)(bx * 128 + sr) * K + scol;
  char* lA0 = (char*)lA + wid * 2048;
  char* lB0 = (char*)lB + wid * 2048;

  f32x4 acc[4][4] = {};
  const int arow = wm * 64, brow = wn * 64;

  for (int kk = 0; kk < K; kk += 32){
    __syncthreads();
    gload16(pa + kk,                    lA0);
    gload16(pa + (size_t)16 * K + kk,   lA0 + 1024);
    gload16(pb + kk,                    lB0);
    gload16(pb + (size_t)16 * K + kk,   lB0 + 1024);
    __syncthreads();
    bf16x8 af[4], bfr[4];
    #pragma unroll
    for (int m = 0; m < 4; m++)
      af[m] = *reinterpret_cast<const bf16x8*>(&lA[(arow + m * 16 + fr) * 32 + fq * 8]);
    #pragma unroll
    for (int n = 0; n < 4; n++)
      bfr[n] = *reinterpret_cast<const bf16x8*>(&lB[(brow + n * 16 + fr) * 32 + fq * 8]);
    #pragma unroll
    for (int m = 0; m < 4; m++)
      #pragma unroll
      for (int n = 0; n < 4; n++)
        acc[m][n] = __builtin_amdgcn_mfma_f32_16x16x32_bf16(af[m], bfr[n], acc[m][n], 0, 0, 0);
  }
  const int orow = by * 128 + wm * 64 + fq * 4;
  const int ocol = bx * 128 + wn * 64 + fr;
  #pragma unroll
  for (int m = 0; m < 4; m++)
    #pragma unroll
    for (int n = 0; n < 4; n++)
      #pragma unroll
      for (int i = 0; i < 4; i++)
        C[(size_t)(orow + m * 16 + i) * N + ocol + n * 16] = acc[m][n][i];
}

// ---------------- RoPE apply + [b][s][e] -> [b][h][s][d] transpose + bf16 quantize ----------------
__global__ void k_rope_apply(const float* __restrict__ X, const float* __restrict__ ct,
                             const float* __restrict__ st, ushort* __restrict__ out){
  int idx = blockIdx.x * 256 + threadIdx.x;
  if (idx >= BB * S_LEN * NH * 64) return;
  int i = idx & 63; int t = idx >> 6;
  int h = t & (NH - 1); t >>= 4;
  int s = t & (S_LEN - 1); int b = t >> 11;
  float2 eo = reinterpret_cast<const float2*>(X + (size_t)(b * S_LEN + s) * DM + h * DK)[i];
  float c = ct[s * 64 + i], sn = st[s * 64 + i];
  float oe = eo.x * c - eo.y * sn;
  float oo = eo.x * sn + eo.y * c;
  unsigned pack = (unsigned)f2bf(oe) | ((unsigned)f2bf(oo) << 16);
  reinterpret_cast<unsigned*>(out + ((size_t)(b * NH + h) * S_LEN + s) * DK)[i] = pack;
}

// ---------------- V: [b][s][e] -> Vt[b][h][d][s] bf16 (tiled transpose) ----------------
__global__ void k_vtrans(const float* __restrict__ X, ushort* __restrict__ Vt){
  __shared__ float tile[32][33];
  int s0 = blockIdx.x * 32, d0 = blockIdx.y * 32;
  int bh = blockIdx.z; int b = bh >> 4, h = bh & 15;
  int t = threadIdx.x;
  int r = t >> 3, c4 = (t & 7) * 4;
  float4 v = *reinterpret_cast<const float4*>(X + (size_t)(b * S_LEN + s0 + r) * DM + h * DK + d0 + c4);
  tile[r][c4] = v.x; tile[r][c4 + 1] = v.y; tile[r][c4 + 2] = v.z; tile[r][c4 + 3] = v.w;
  __syncthreads();
  int dl = t >> 3, s4 = (t & 7) * 4;
  ushort4 o;
  o.x = f2bf(tile[s4][dl]); o.y = f2bf(tile[s4 + 1][dl]);
  o.z = f2bf(tile[s4 + 2][dl]); o.w = f2bf(tile[s4 + 3][dl]);
  *reinterpret_cast<ushort4*>(Vt + (size_t)(bh * DK + d0 + dl) * S_LEN + s0 + s4) = o;
}

// ---------------- causal flash attention ----------------
// grid (S/128, B*H), 4 waves. Wave owns 32 q-rows (2 x 16-frags). KVBLK=64.
// K/V: global_load_lds + pre-swizzled source (XOR (row&7)<<4), double-buffered, 1 barrier/tile.
__launch_bounds__(256)
__global__ void k_attn(const ushort* __restrict__ Q, const ushort* __restrict__ K,
                       const ushort* __restrict__ Vt, ushort* __restrict__ O){
  __shared__ short Kt[2][64 * 128];   // [kv][d], swizzled
  __shared__ short Vl[2][128 * 64];   // [d][kv], swizzled
  __shared__ short Pl[4][32 * 64];    // per-wave [q][kv], swizzled
  const int tid = threadIdx.x, lane = tid & 63, wid = tid >> 6;
  const int bh = blockIdx.y, b = bh >> 4, h = bh & 15;
  const int q0 = blockIdx.x * 128;
  const int qr = q0 + wid * 32;
  const int fr = lane & 15, fq = lane >> 4;
  const int swz = (fr & 7) << 4;

  const ushort* kb = K  + (size_t)bh * S_LEN * DK;
  const ushort* vb = Vt + (size_t)bh * DK * S_LEN;

  bf16x8 qf[2][4];
  #pragma unroll
  for (int m = 0; m < 2; m++)
    #pragma unroll
    for (int c = 0; c < 4; c++)
      qf[m][c] = *reinterpret_cast<const bf16x8*>(
          Q + ((size_t)bh * S_LEN + qr + m * 16 + fr) * DK + c * 32 + fq * 8);

  // staging address precompute (per-lane global source, pre-swizzled)
  int kr[4], kc[4], vd[4], vc[4];
  #pragma unroll
  for (int j = 0; j < 4; j++){
    int ins = wid * 4 + j;
    kr[j] = ins * 4 + (lane >> 4);
    kc[j] = 8 * ((lane & 15) ^ (kr[j] & 7));
    vd[j] = ins * 8 + (lane >> 3);
    vc[j] = 8 * ((lane & 7) ^ (vd[j] & 7));
  }

  float mi[2][4], li[2][4], scl[2][4];
  #pragma unroll
  for (int m = 0; m < 2; m++)
    #pragma unroll
    for (int i = 0; i < 4; i++){ mi[m][i] = -1e30f; li[m][i] = 0.f; }
  f32x4 accO[8][2] = {};

  const int nt = q0 / 64 + 2;
  const float scale = 0.08838834764831845f;   // 1/sqrt(128)

  // prologue: stage tile 0
  #pragma unroll
  for (int j = 0; j < 4; j++){
    gload16(kb + (size_t)kr[j] * DK + kc[j],        (char*)(&Kt[0][0]) + (wid * 4 + j) * 1024);
    gload16(vb + (size_t)vd[j] * S_LEN + vc[j],     (char*)(&Vl[0][0]) + (wid * 4 + j) * 1024);
  }
  __syncthreads();

  for (int kt = 0; kt < nt; kt++){
    const int k0 = kt * 64;
    const int cur = kt & 1;
    if (kt + 1 < nt){
      const int k1 = k0 + 64;
      #pragma unroll
      for (int j = 0; j < 4; j++){
        gload16(kb + (size_t)(k1 + kr[j]) * DK + kc[j],    (char*)(&Kt[cur ^ 1][0]) + (wid * 4 + j) * 1024);
        gload16(vb + (size_t)vd[j] * S_LEN + k1 + vc[j],   (char*)(&Vl[cur ^ 1][0]) + (wid * 4 + j) * 1024);
      }
    }
    const char* KtB = (const char*)(&Kt[cur][0]);
    const char* VlB = (const char*)(&Vl[cur][0]);
    char* PlB = (char*)(&Pl[wid][0]);

    // QK^T -> S[q][kv]
    f32x4 sc[2][4] = {};
    #pragma unroll
    for (int ch = 0; ch < 4; ch++)
      #pragma unroll
      for (int c = 0; c < 4; c++){
        bf16x8 kf = *reinterpret_cast<const bf16x8*>(
            KtB + (ch * 16 + fr) * 256 + ((c * 64 + fq * 16) ^ swz));
        sc[0][ch] = __builtin_amdgcn_mfma_f32_16x16x32_bf16(qf[0][c], kf, sc[0][ch], 0, 0, 0);
        sc[1][ch] = __builtin_amdgcn_mfma_f32_16x16x32_bf16(qf[1][c], kf, sc[1][ch], 0, 0, 0);
      }

    // scale + causal mask + online softmax (per m-frag)
    #pragma unroll
    for (int m = 0; m < 2; m++){
      const bool needmask = (k0 + 63 > qr + m * 16);
      #pragma unroll
      for (int ch = 0; ch < 4; ch++)
        #pragma unroll
        for (int i = 0; i < 4; i++){
          float v = sc[m][ch][i] * scale;
          if (needmask && (k0 + ch * 16 + fr > qr + m * 16 + fq * 4 + i)) v = -1e30f;
          sc[m][ch][i] = v;
        }
      f32x4 mx;
      #pragma unroll
      for (int i = 0; i < 4; i++)
        mx[i] = fmaxf(fmaxf(sc[m][0][i], sc[m][1][i]), fmaxf(sc[m][2][i], sc[m][3][i]));
      #pragma unroll
      for (int off = 1; off < 16; off <<= 1)
        #pragma unroll
        for (int i = 0; i < 4; i++) mx[i] = fmaxf(mx[i], __shfl_xor(mx[i], off));
      #pragma unroll
      for (int i = 0; i < 4; i++){
        float mn = fmaxf(mi[m][i], mx[i]);
        float s = __expf(mi[m][i] - mn);
        mi[m][i] = mn;
        scl[m][i] = s;
      }
      #pragma unroll
      for (int ch = 0; ch < 4; ch++)
        #pragma unroll
        for (int i = 0; i < 4; i++) sc[m][ch][i] = __expf(sc[m][ch][i] - mi[m][i]);
      f32x4 rs;
      #pragma unroll
      for (int i = 0; i < 4; i++)
        rs[i] = (sc[m][0][i] + sc[m][1][i]) + (sc[m][2][i] + sc[m][3][i]);
      #pragma unroll
      for (int off = 1; off < 16; off <<= 1)
        #pragma unroll
        for (int i = 0; i < 4; i++) rs[i] += __shfl_xor(rs[i], off);
      #pragma unroll
      for (int i = 0; i < 4; i++) li[m][i] = li[m][i] * scl[m][i] + rs[i];
      #pragma unroll
      for (int dt = 0; dt < 8; dt++)
        #pragma unroll
        for (int i = 0; i < 4; i++) accO[dt][m][i] *= scl[m][i];

      // P -> LDS (bf16, swizzled)
      #pragma unroll
      for (int ch = 0; ch < 4; ch++)
        #pragma unroll
        for (int i = 0; i < 4; i++){
          int q = fq * 4 + i;
          int off = (m * 16 + q) * 128 + ((ch * 32 + fr * 2) ^ ((q & 7) << 4));
          *reinterpret_cast<short*>(PlB + off) = (short)f2bf(sc[m][ch][i]);
        }
    }

    // PV: O += P * V
    #pragma unroll
    for (int c = 0; c < 2; c++){
      bf16x8 pf0 = *reinterpret_cast<const bf16x8*>(PlB + fr * 128 + ((c * 64 + fq * 16) ^ swz));
      bf16x8 pf1 = *reinterpret_cast<const bf16x8*>(PlB + (16 + fr) * 128 + ((c * 64 + fq * 16) ^ swz));
      #pragma unroll
      for (int dt = 0; dt < 8; dt++){
        bf16x8 vf = *reinterpret_cast<const bf16x8*>(
            VlB + (dt * 16 + fr) * 128 + ((c * 64 + fq * 16) ^ swz));
        accO[dt][0] = __builtin_amdgcn_mfma_f32_16x16x32_bf16(pf0, vf, accO[dt][0], 0, 0, 0);
        accO[dt][1] = __builtin_amdgcn_mfma_f32_16x16x32_bf16(pf1, vf, accO[dt][1], 0, 0, 0);
      }
    }
    __syncthreads();
  }

  ushort* ob = O + (size_t)b * S_LEN * DM;
  #pragma unroll
  for (int m = 0; m < 2; m++){
    float inv[4];
    #pragma unroll
    for (int i = 0; i < 4; i++) inv[i] = 1.f / li[m][i];
    #pragma unroll
    for (int dt = 0; dt < 8; dt++)
      #pragma unroll
      for (int i = 0; i < 4; i++){
        int row = qr + m * 16 + fq * 4 + i;
        ob[(size_t)row * DM + h * DK + dt * 16 + fr] = f2bf(accO[dt][m][i] * inv[i]);
      }
  }
}

extern "C" void kernel_launch(void* const* d_in, const int* in_sizes, int n_in,
                              void* d_out, int out_size, void* d_ws, size_t ws_size,
                              hipStream_t stream){
  const float* x  = (const float*)d_in[0];
  const float* wq = (const float*)d_in[1];
  const float* wk = (const float*)d_in[2];
  const float* wv = (const float*)d_in[3];
  const float* wo = (const float*)d_in[4];
  const int* pos  = (const int*)d_in[5];
  float* out = (float*)d_out;

  char* ws = (char*)d_ws;
  ushort* xb = (ushort*)(ws);                        // 16 MiB  x bf16
  ushort* wb = (ushort*)(ws + 16777216);             //  8 MiB  current weight bf16
  float*  scr = (float*)(ws + 25165824);             // 32 MiB  fp32 projection scratch
  ushort* Ob = (ushort*)(ws + 25165824);             //   (aliases scr after V consumed)
  ushort* Qh = (ushort*)(ws + 58720256);             // 16 MiB
  ushort* Kh = (ushort*)(ws + 75497472);             // 16 MiB
  ushort* Vt = (ushort*)(ws + 92274688);             // 16 MiB
  float*  ct = (float*)(ws + 109051904);             // 512 KiB
  float*  st = (float*)(ws + 109576192);             // 512 KiB

  const int M = BB * S_LEN, N = DM, K = DM;
  dim3 gblk(N / 128, M / 128);
  const int nw4 = DM * DM / 4;

  k_f32_to_bf16<<<(M * DM / 4) / 256, 256, 0, stream>>>(x, xb, M * DM / 4);
  k_rope_table<<<(S_LEN * 64) / 256, 256, 0, stream>>>(pos, ct, st);

  k_f32_to_bf16<<<nw4 / 256, 256, 0, stream>>>(wq, wb, nw4);
  k_gemm_bt<<<gblk, 256, 0, stream>>>(xb, wb, scr, M, N, K);
  k_rope_apply<<<(BB * S_LEN * NH * 64) / 256, 256, 0, stream>>>(scr, ct, st, Qh);

  k_f32_to_bf16<<<nw4 / 256, 256, 0, stream>>>(wk, wb, nw4);
  k_gemm_bt<<<gblk, 256, 0, stream>>>(xb, wb, scr, M, N, K);
  k_rope_apply<<<(BB * S_LEN * NH * 64) / 256, 256, 0, stream>>>(scr, ct, st, Kh);

  k_f32_to_bf16<<<nw4 / 256, 256, 0, stream>>>(wv, wb, nw4);
  k_gemm_bt<<<gblk, 256, 0, stream>>>(xb, wb, scr, M, N, K);
  k_vtrans<<<dim3(S_LEN / 32, DK / 32, BH), 256, 0, stream>>>(scr, Vt);

  k_attn<<<dim3(S_LEN / 128, BH), 256, 0, stream>>>(Qh, Kh, Vt, Ob);

  k_f32_to_bf16<<<nw4 / 256, 256, 0, stream>>>(wo, wb, nw4);
  k_gemm_bt<<<gblk, 256, 0, stream>>>(Ob, wb, out, M, N, K);
}

// Round 3
// 440.213 us; speedup vs baseline: 1.1812x; 1.1526x over previous
//
#include <hip/hip_runtime.h>

#define S_LEN 2048
#define DM 2048
#define NH 16
#define DK 128
#define BB 2
#define BH (BB*NH)

typedef float f32x4 __attribute__((ext_vector_type(4)));
typedef __bf16 bf16x8 __attribute__((ext_vector_type(8)));
typedef unsigned int u32;

#define AS1 __attribute__((address_space(1)))
#define AS3 __attribute__((address_space(3)))

__device__ inline void gload16(const void* g, void* l){
  __builtin_amdgcn_global_load_lds((AS1 const u32*)g, (AS3 u32*)l, 16, 0, 0);
}

__device__ inline ushort f2bf(float f){
  unsigned u = __float_as_uint(f);
  u = (u + 0x7FFFu + ((u >> 16) & 1u)) >> 16;
  return (ushort)u;
}

// ---------------- fp32 -> bf16 (vectorized) ----------------
__global__ void k_f32_to_bf16(const float* __restrict__ in, ushort* __restrict__ out, int n4){
  int i = blockIdx.x * blockDim.x + threadIdx.x;
  if (i >= n4) return;
  float4 v = reinterpret_cast<const float4*>(in)[i];
  ushort4 o;
  o.x = f2bf(v.x); o.y = f2bf(v.y); o.z = f2bf(v.z); o.w = f2bf(v.w);
  reinterpret_cast<ushort4*>(out)[i] = o;
}

// ---------------- rope cos/sin table [S][64] ----------------
__global__ void k_rope_table(const int* __restrict__ pos, float* __restrict__ ct, float* __restrict__ st){
  int idx = blockIdx.x * 256 + threadIdx.x;
  if (idx >= S_LEN * 64) return;
  int s = idx >> 6, i = idx & 63;
  float inv = expf(-0.14391156831212787f * (float)i);
  float f = (float)pos[s] * inv;
  ct[idx] = cosf(f);
  st[idx] = sinf(f);
}

// ---------------- GEMM: C[M][N] = A[M][K] * Bt[N][K]^T  (m97 structure) ----------------
__launch_bounds__(256)
__global__ void k_gemm_bt(const ushort* __restrict__ A, const ushort* __restrict__ Bt,
                          float* __restrict__ C, int M, int N, int K){
  __shared__ short lA[128 * 32];
  __shared__ short lB[128 * 32];
  const int tid = threadIdx.x;
  const int lane = tid & 63, wid = tid >> 6;
  const int wm = wid >> 1, wn = wid & 1;
  const int bx = blockIdx.x, by = blockIdx.y;
  const int fr = lane & 15, fq = lane >> 4;

  const int sr = wid * 32 + (lane >> 2);
  const int scol = (lane & 3) * 8;
  const ushort* pa = A  + (size_t)(by * 128 + sr) * K + scol;
  const ushort* pb = Bt + (size_t)(bx * 128 + sr) * K + scol;
  char* lA0 = (char*)lA + wid * 2048;
  char* lB0 = (char*)lB + wid * 2048;

  f32x4 acc[4][4] = {};
  const int arow = wm * 64, brow = wn * 64;

  for (int kk = 0; kk < K; kk += 32){
    __syncthreads();
    gload16(pa + kk,                    lA0);
    gload16(pa + (size_t)16 * K + kk,   lA0 + 1024);
    gload16(pb + kk,                    lB0);
    gload16(pb + (size_t)16 * K + kk,   lB0 + 1024);
    __syncthreads();
    bf16x8 af[4], bfr[4];
    #pragma unroll
    for (int m = 0; m < 4; m++)
      af[m] = *reinterpret_cast<const bf16x8*>(&lA[(arow + m * 16 + fr) * 32 + fq * 8]);
    #pragma unroll
    for (int n = 0; n < 4; n++)
      bfr[n] = *reinterpret_cast<const bf16x8*>(&lB[(brow + n * 16 + fr) * 32 + fq * 8]);
    #pragma unroll
    for (int m = 0; m < 4; m++)
      #pragma unroll
      for (int n = 0; n < 4; n++)
        acc[m][n] = __builtin_amdgcn_mfma_f32_16x16x32_bf16(af[m], bfr[n], acc[m][n], 0, 0, 0);
  }
  const int orow = by * 128 + wm * 64 + fq * 4;
  const int ocol = bx * 128 + wn * 64 + fr;
  #pragma unroll
  for (int m = 0; m < 4; m++)
    #pragma unroll
    for (int n = 0; n < 4; n++)
      #pragma unroll
      for (int i = 0; i < 4; i++)
        C[(size_t)(orow + m * 16 + i) * N + ocol + n * 16] = acc[m][n][i];
}

// ---------------- RoPE apply + [b][s][e] -> [b][h][s][d] transpose + bf16 quantize ----------------
__global__ void k_rope_apply(const float* __restrict__ X, const float* __restrict__ ct,
                             const float* __restrict__ st, ushort* __restrict__ out){
  int idx = blockIdx.x * 256 + threadIdx.x;
  if (idx >= BB * S_LEN * NH * 64) return;
  int i = idx & 63; int t = idx >> 6;
  int h = t & (NH - 1); t >>= 4;
  int s = t & (S_LEN - 1); int b = t >> 11;
  float2 eo = reinterpret_cast<const float2*>(X + (size_t)(b * S_LEN + s) * DM + h * DK)[i];
  float c = ct[s * 64 + i], sn = st[s * 64 + i];
  float oe = eo.x * c - eo.y * sn;
  float oo = eo.x * sn + eo.y * c;
  unsigned pack = (unsigned)f2bf(oe) | ((unsigned)f2bf(oo) << 16);
  reinterpret_cast<unsigned*>(out + ((size_t)(b * NH + h) * S_LEN + s) * DK)[i] = pack;
}

// ---------------- V: [b][s][e] -> Vt[b][h][d][s] bf16 (tiled transpose) ----------------
__global__ void k_vtrans(const float* __restrict__ X, ushort* __restrict__ Vt){
  __shared__ float tile[32][33];
  int s0 = blockIdx.x * 32, d0 = blockIdx.y * 32;
  int bh = blockIdx.z; int b = bh >> 4, h = bh & 15;
  int t = threadIdx.x;
  int r = t >> 3, c4 = (t & 7) * 4;
  float4 v = *reinterpret_cast<const float4*>(X + (size_t)(b * S_LEN + s0 + r) * DM + h * DK + d0 + c4);
  tile[r][c4] = v.x; tile[r][c4 + 1] = v.y; tile[r][c4 + 2] = v.z; tile[r][c4 + 3] = v.w;
  __syncthreads();
  int dl = t >> 3, s4 = (t & 7) * 4;
  ushort4 o;
  o.x = f2bf(tile[s4][dl]); o.y = f2bf(tile[s4 + 1][dl]);
  o.z = f2bf(tile[s4 + 2][dl]); o.w = f2bf(tile[s4 + 3][dl]);
  *reinterpret_cast<ushort4*>(Vt + (size_t)(bh * DK + d0 + dl) * S_LEN + s0 + s4) = o;
}

// ---------------- causal flash attention: 1 wave / block, no barriers ----------------
// grid 2048 blocks x 64 threads. Block (qi,bh): wave owns q rows [32*qi, 32*qi+32).
// K, Vt fragments read directly global->reg (L2-resident). Heavy-first block order.
// P transpose via private 4KB LDS, XOR-swizzled, same-wave in-order DS (no barrier).
__launch_bounds__(64)
__global__ void k_attn(const ushort* __restrict__ Q, const ushort* __restrict__ K,
                       const ushort* __restrict__ Vt, ushort* __restrict__ O){
  __shared__ short Pl[32 * 64];
  const int lane = threadIdx.x;
  const int bid = blockIdx.x;
  const int qi = 63 - (bid >> 5);          // heavy q-tiles launch first (LPT)
  const int bh = bid & 31;                 // consecutive bids spread bh across XCDs
  const int b = bh >> 4, h = bh & 15;
  const int qr = qi * 32;
  const int fr = lane & 15, fq = lane >> 4;

  const ushort* kb = K  + (size_t)bh * S_LEN * DK;
  const ushort* vb = Vt + (size_t)bh * DK * S_LEN;
  char* PlB = (char*)Pl;

  bf16x8 qf[2][4];
  #pragma unroll
  for (int m = 0; m < 2; m++)
    #pragma unroll
    for (int c = 0; c < 4; c++)
      qf[m][c] = *reinterpret_cast<const bf16x8*>(
          Q + ((size_t)bh * S_LEN + qr + m * 16 + fr) * DK + c * 32 + fq * 8);

  float mi[2][4], li[2][4];
  #pragma unroll
  for (int m = 0; m < 2; m++)
    #pragma unroll
    for (int i = 0; i < 4; i++){ mi[m][i] = -1e30f; li[m][i] = 0.f; }
  f32x4 accO[2][8] = {};

  const int nt = qi / 2 + 1;
  const float scale = 0.08838834764831845f;   // 1/sqrt(128)

  for (int kt = 0; kt < nt; kt++){
    const int k0 = kt * 64;

    // ---- QK^T: S[q=32][kv=64], K frags direct from global ----
    f32x4 sc[2][4] = {};
    #pragma unroll
    for (int c = 0; c < 4; c++){
      bf16x8 kf[4];
      #pragma unroll
      for (int ch = 0; ch < 4; ch++)
        kf[ch] = *reinterpret_cast<const bf16x8*>(
            kb + (size_t)(k0 + ch * 16 + fr) * DK + c * 32 + fq * 8);
      #pragma unroll
      for (int ch = 0; ch < 4; ch++){
        sc[0][ch] = __builtin_amdgcn_mfma_f32_16x16x32_bf16(qf[0][c], kf[ch], sc[0][ch], 0, 0, 0);
        sc[1][ch] = __builtin_amdgcn_mfma_f32_16x16x32_bf16(qf[1][c], kf[ch], sc[1][ch], 0, 0, 0);
      }
    }

    // ---- scale + causal mask + online softmax (per 16-row frag) ----
    #pragma unroll
    for (int m = 0; m < 2; m++){
      const int qb = qr + m * 16;
      const bool needmask = (k0 + 63 > qb);
      #pragma unroll
      for (int ch = 0; ch < 4; ch++)
        #pragma unroll
        for (int i = 0; i < 4; i++){
          float v = sc[m][ch][i] * scale;
          if (needmask && (k0 + ch * 16 + fr > qb + fq * 4 + i)) v = -1e30f;
          sc[m][ch][i] = v;
        }
      f32x4 mx;
      #pragma unroll
      for (int i = 0; i < 4; i++)
        mx[i] = fmaxf(fmaxf(sc[m][0][i], sc[m][1][i]), fmaxf(sc[m][2][i], sc[m][3][i]));
      #pragma unroll
      for (int off = 1; off < 16; off <<= 1)
        #pragma unroll
        for (int i = 0; i < 4; i++) mx[i] = fmaxf(mx[i], __shfl_xor(mx[i], off));
      float scl[4];
      #pragma unroll
      for (int i = 0; i < 4; i++){
        float mn = fmaxf(mi[m][i], mx[i]);
        scl[i] = __expf(mi[m][i] - mn);
        mi[m][i] = mn;
      }
      #pragma unroll
      for (int ch = 0; ch < 4; ch++)
        #pragma unroll
        for (int i = 0; i < 4; i++) sc[m][ch][i] = __expf(sc[m][ch][i] - mi[m][i]);
      f32x4 rs;
      #pragma unroll
      for (int i = 0; i < 4; i++)
        rs[i] = (sc[m][0][i] + sc[m][1][i]) + (sc[m][2][i] + sc[m][3][i]);
      #pragma unroll
      for (int off = 1; off < 16; off <<= 1)
        #pragma unroll
        for (int i = 0; i < 4; i++) rs[i] += __shfl_xor(rs[i], off);
      #pragma unroll
      for (int i = 0; i < 4; i++) li[m][i] = li[m][i] * scl[i] + rs[i];
      #pragma unroll
      for (int dt = 0; dt < 8; dt++)
        #pragma unroll
        for (int i = 0; i < 4; i++) accO[m][dt][i] *= scl[i];

      // P -> LDS (bf16, swizzled: byte ^= (q&7)<<4)
      #pragma unroll
      for (int ch = 0; ch < 4; ch++)
        #pragma unroll
        for (int i = 0; i < 4; i++){
          int q = m * 16 + fq * 4 + i;
          int off = q * 128 + ((ch * 32 + fr * 2) ^ ((q & 7) << 4));
          *reinterpret_cast<short*>(PlB + off) = (short)f2bf(sc[m][ch][i]);
        }
    }

    // ---- P fragments (A-layout) back from LDS ----
    bf16x8 pf[2][2];
    #pragma unroll
    for (int m = 0; m < 2; m++)
      #pragma unroll
      for (int c2 = 0; c2 < 2; c2++)
        pf[m][c2] = *reinterpret_cast<const bf16x8*>(
            PlB + (m * 16 + fr) * 128 + ((c2 * 64 + fq * 16) ^ ((fr & 7) << 4)));

    // ---- PV: O += P * V, V frags direct from Vt[d][s] ----
    #pragma unroll
    for (int dt = 0; dt < 8; dt++){
      #pragma unroll
      for (int c2 = 0; c2 < 2; c2++){
        bf16x8 vf = *reinterpret_cast<const bf16x8*>(
            vb + (size_t)(dt * 16 + fr) * S_LEN + k0 + c2 * 32 + fq * 8);
        accO[0][dt] = __builtin_amdgcn_mfma_f32_16x16x32_bf16(pf[0][c2], vf, accO[0][dt], 0, 0, 0);
        accO[1][dt] = __builtin_amdgcn_mfma_f32_16x16x32_bf16(pf[1][c2], vf, accO[1][dt], 0, 0, 0);
      }
    }
  }

  ushort* ob = O + (size_t)b * S_LEN * DM;
  #pragma unroll
  for (int m = 0; m < 2; m++){
    float inv[4];
    #pragma unroll
    for (int i = 0; i < 4; i++) inv[i] = 1.f / li[m][i];
    #pragma unroll
    for (int dt = 0; dt < 8; dt++)
      #pragma unroll
      for (int i = 0; i < 4; i++){
        int row = qr + m * 16 + fq * 4 + i;
        ob[(size_t)row * DM + h * DK + dt * 16 + fr] = f2bf(accO[m][dt][i] * inv[i]);
      }
  }
}

extern "C" void kernel_launch(void* const* d_in, const int* in_sizes, int n_in,
                              void* d_out, int out_size, void* d_ws, size_t ws_size,
                              hipStream_t stream){
  const float* x  = (const float*)d_in[0];
  const float* wq = (const float*)d_in[1];
  const float* wk = (const float*)d_in[2];
  const float* wv = (const float*)d_in[3];
  const float* wo = (const float*)d_in[4];
  const int* pos  = (const int*)d_in[5];
  float* out = (float*)d_out;

  char* ws = (char*)d_ws;
  ushort* xb = (ushort*)(ws);                        // 16 MiB  x bf16
  ushort* wb = (ushort*)(ws + 16777216);             //  8 MiB  current weight bf16
  float*  scr = (float*)(ws + 25165824);             // 32 MiB  fp32 projection scratch
  ushort* Ob = (ushort*)(ws + 25165824);             //   (aliases scr after V consumed)
  ushort* Qh = (ushort*)(ws + 58720256);             // 16 MiB
  ushort* Kh = (ushort*)(ws + 75497472);             // 16 MiB
  ushort* Vt = (ushort*)(ws + 92274688);             // 16 MiB
  float*  ct = (float*)(ws + 109051904);             // 512 KiB
  float*  st = (float*)(ws + 109576192);             // 512 KiB

  const int M = BB * S_LEN, N = DM, K = DM;
  dim3 gblk(N / 128, M / 128);
  const int nw4 = DM * DM / 4;

  k_f32_to_bf16<<<(M * DM / 4) / 256, 256, 0, stream>>>(x, xb, M * DM / 4);
  k_rope_table<<<(S_LEN * 64) / 256, 256, 0, stream>>>(pos, ct, st);

  k_f32_to_bf16<<<nw4 / 256, 256, 0, stream>>>(wq, wb, nw4);
  k_gemm_bt<<<gblk, 256, 0, stream>>>(xb, wb, scr, M, N, K);
  k_rope_apply<<<(BB * S_LEN * NH * 64) / 256, 256, 0, stream>>>(scr, ct, st, Qh);

  k_f32_to_bf16<<<nw4 / 256, 256, 0, stream>>>(wk, wb, nw4);
  k_gemm_bt<<<gblk, 256, 0, stream>>>(xb, wb, scr, M, N, K);
  k_rope_apply<<<(BB * S_LEN * NH * 64) / 256, 256, 0, stream>>>(scr, ct, st, Kh);

  k_f32_to_bf16<<<nw4 / 256, 256, 0, stream>>>(wv, wb, nw4);
  k_gemm_bt<<<gblk, 256, 0, stream>>>(xb, wb, scr, M, N, K);
  k_vtrans<<<dim3(S_LEN / 32, DK / 32, BH), 256, 0, stream>>>(scr, Vt);

  k_attn<<<dim3(64 * BH), 64, 0, stream>>>(Qh, Kh, Vt, Ob);

  k_f32_to_bf16<<<nw4 / 256, 256, 0, stream>>>(wo, wb, nw4);
  k_gemm_bt<<<gblk, 256, 0, stream>>>(Ob, wb, out, M, N, K);
}